// Round 8
// baseline (88.207 us; speedup 1.0000x reference)
//
#include <hip/hip_runtime.h>
#include <cmath>

// Problem constants (fixed by the reference's init kwargs):
//   POS_FREQS=31, W_MIN=0.1, W_MAX=1.0, PATCH=16 -> grid H=64 (row 63 padded), W=32
//   batch_triangles: [64,128,3,2] f32, lengths: [64] i32
//   outputs: mag [64,1,64,32] f32 then phase [64,1,64,32] f32, concatenated flat.
#define BB     64
#define MAXN   128
#define HH     64
#define WW     32
#define NFREQ  (HH*WW)      // 2048
#define BLK    256
#define PCHUNKS (NFREQ/BLK) // 8 point-chunks per batch elem (1 point/thread, as R5)
#define TRI_CHUNK 16
#define QQ     (MAXN/TRI_CHUNK) // 8 triangle chunks
// ws layout:
//   [0)            float2 partial[QQ][BB][NFREQ]   = 8 MB
//   [+8MB)         float4 triA[BB][MAXN]           = 128 KB
//                  float4 triB[BB][MAXN]           = 128 KB
//                  float  Wx[64], Wy[32]
#define PARTIAL_F2   ((size_t)QQ * BB * NFREQ)          // float2 count
#define NTRI         (BB * MAXN)

// sin(2*pi*x), cos(2*pi*x) via hardware v_sin_f32/v_cos_f32 (input in
// REVOLUTIONS, reduced to [0,1) with v_fract_f32 first).
__device__ __forceinline__ void sincos_2pi(float x, float* s, float* c) {
    float r = __builtin_amdgcn_fractf(x);
    *s = __builtin_amdgcn_sinf(r);
    *c = __builtin_amdgcn_cosf(r);
}

// Fully BRANCHLESS (point, triangle) evaluation — IDENTICAL text to the
// round-5 passing kernel (absmax 0.015625). Do not perturb.
// Rotated frame: E_x = exp(-2*pi*i*t_x), t_q = U*xq+V*yq, t_r = t_q+U_,
// t_s = t_r+V_.  All four reference cases share:
//   re =  A*c_s + B*c_r + C*c_q + D*s_r + E*s_q
//   im = -A*s_s - B*s_r - C*s_q + D*c_r + E*c_q
// with k = sgn*area/(4pi^2*den):
//   normal: A=-U_, B=S,  C=-V_, D=0,     E=0;     den=U_*V_*S, sgn=+2
//   diag  : A=0,   B=1,  C=-1,  D=0,     E=2piU_; den=U_^2,    sgn=-2
//   u_mask: A=1,   B=0,  C=-1,  D=0,     E=2piV_; den=V_^2,    sgn=-2
//   v_mask: A=0,   B=1,  C=-1,  D=2piU_, E=0;     den=U_^2,    sgn=+2
//   zero  : k=0, add area directly.
__device__ __forceinline__ void eval_tri(
    float U, float V, float4 A4, float4 B4, float& accR, float& accI,
    float TWOPI, float FOUR_PI2)
{
    const float xq = A4.x,  yq = A4.y,  e1x = A4.z, e1y = A4.w;
    const float e2x = B4.x, e2y = B4.y, area = B4.z;

    // Mask-determining quantities: plain mul/mul/add (no FMA contraction)
    // to reproduce the reference's exact-zero pattern.
    const float U_ = __fadd_rn(__fmul_rn(U, e1x), __fmul_rn(V, e1y));
    const float V_ = __fadd_rn(__fmul_rn(U, e2x), __fmul_rn(V, e2y));
    const float S  = __fadd_rn(U_, V_);

    const bool uz   = (U_ == 0.0f);
    const bool vz   = (V_ == 0.0f);
    const bool sz   = (S  == 0.0f);
    const bool zero = uz && vz;
    const bool diag = sz && !zero;      // uz -> (sz<->vz), so cases exclusive
    const bool u_m  = uz && !zero;
    const bool v_m  = vz && !zero;
    const bool nrm  = !(uz || vz || sz);

    // Exponential args (not mask-relevant; FMA fine). t_r/t_s exact when
    // U_/V_ are exactly 0 (adding exact zero), which the special cases need.
    const float t_q = U * xq + V * yq;
    const float t_r = t_q + U_;
    const float t_s = t_r + V_;

    float s_q, c_q, s_r, c_r, s_s, c_s;
    sincos_2pi(t_q, &s_q, &c_q);
    sincos_2pi(t_r, &s_r, &c_r);
    sincos_2pi(t_s, &s_s, &c_s);

    const float twU = TWOPI * U_;
    const float twV = TWOPI * V_;

    const float Ac = nrm ? -U_ : (u_m ? 1.0f : 0.0f);
    const float Bc = nrm ?  S  : ((diag || v_m) ? 1.0f : 0.0f);
    const float Cc = nrm ? -V_ : -1.0f;
    const float Dc = v_m  ? twU : 0.0f;
    const float Ec = diag ? twU : (u_m ? twV : 0.0f);

    const float d1  = u_m ? V_ : U_;
    const float den = nrm ? (U_ * V_) * S : d1 * d1;
    const float p1  = __builtin_amdgcn_rcpf(FOUR_PI2 * den);
    const float sgn = (diag || u_m) ? -2.0f : 2.0f;
    const float k   = zero ? 0.0f : sgn * area * p1;   // cndmask kills inf path

    const float re =  Ac * c_s + Bc * c_r + Cc * c_q + Dc * s_r + Ec * s_q;
    const float im = -(Ac * s_s + Bc * s_r + Cc * s_q) + Dc * c_r + Ec * c_q;

    accR = fmaf(k, re, accR) + (zero ? area : 0.0f);
    accI = fmaf(k, im, accI);
}

// One-time setup: frequency tables (same double-precision path as numpy,
// bit-identical grid) + triangle preprocessing (edges/area) — hoisted out of
// the hot kernel so it never touches f64 or redundant per-block work.
__global__ __launch_bounds__(BLK) void poly_cft_setup(
    const float* __restrict__ tris,   // [64,128,3,2]
    float4*      __restrict__ triA,   // [BB*MAXN]
    float4*      __restrict__ triB,   // [BB*MAXN]
    float*       __restrict__ Wtab)   // Wx[64] then Wy[32]
{
    __shared__ float s_posw[31];
    if (threadIdx.x < 31) {
        double g = pow(10.0, 1.0 / 30.0);
        s_posw[threadIdx.x] = (float)(0.1 * pow(g, (double)threadIdx.x));
    }
    __syncthreads();

    if (threadIdx.x < 64) {
        const int h = threadIdx.x;
        float u;
        if (h < 31)       u = -s_posw[30 - h];
        else if (h == 31) u = 0.0f;
        else if (h < 63)  u = s_posw[h - 32];
        else              u = 0.0f;           // padded row
        Wtab[h] = u;
    }
    if (threadIdx.x < 32) {
        Wtab[64 + threadIdx.x] = (threadIdx.x == 0) ? 0.0f : s_posw[threadIdx.x - 1];
    }

    for (int i = threadIdx.x; i < NTRI; i += BLK) {
        const float* t = tris + (size_t)i * 6;
        float xq = t[0], yq = t[1];
        float xr = t[2], yr = t[3];
        float xs = t[4], ys = t[5];
        float det  = xq * (yr - ys) + xr * (ys - yq) + xs * (yq - yr);
        float area = fabsf(0.5f * det);
        triA[i] = make_float4(xq, yq, xr - xq, yr - yq);
        triB[i] = make_float4(xs - xr, ys - yr, area, 0.0f);
    }
}

// Structure identical to the round-5 passing kernel: 1 point per thread,
// 8 point-chunks; only the per-block f64 table + triangle preprocessing
// are replaced by loads of the setup kernel's output.
__global__ __launch_bounds__(BLK) void poly_cft_partial(
    const int*    __restrict__ lengths, // [64]
    const float4* __restrict__ triA,
    const float4* __restrict__ triB,
    const float*  __restrict__ Wtab,    // Wx[64], Wy[32]
    float2*       __restrict__ ws)      // [QQ][BB][NFREQ] partial sums
{
    __shared__ float4 sA[TRI_CHUNK];
    __shared__ float4 sB[TRI_CHUNK];

    const int pc = blockIdx.x;                 // 0..7 point chunk
    const int q  = blockIdx.y;                 // 0..7 triangle chunk
    const int b  = blockIdx.z;                 // 0..63 batch elem
    const int p  = (pc << 8) | threadIdx.x;    // 0..2047 freq point
    const int h  = p >> 5;
    const int w  = p & 31;

    const int N   = lengths[b];
    const int n0  = q * TRI_CHUNK;
    const int cnt = min(n0 + TRI_CHUNK, N) - n0;   // may be <= 0

    // Entire chunk out of range: nothing to do — finalize only reads chunks
    // q < ceil(N/TRI_CHUNK), so no zero-write is needed.
    if (cnt <= 0) return;

    // Stage TRI_CHUNK preprocessed triangles; pad invalid slots with
    // degenerate zeros (U_=V_=0 -> zero case -> contributes exactly area=0).
    if (threadIdx.x < 2 * TRI_CHUNK) {
        const int n   = threadIdx.x >> 1;      // triangle slot
        const int sel = threadIdx.x & 1;       // 0 -> A, 1 -> B
        float4 v = make_float4(0.0f, 0.0f, 0.0f, 0.0f);
        if (n < cnt) {
            const size_t gi = (size_t)b * MAXN + n0 + n;
            v = sel ? triB[gi] : triA[gi];
        }
        if (sel) sB[n] = v; else sA[n] = v;
    }
    __syncthreads();

    const float U = Wtab[h];
    const float V = Wtab[64 + w];

    // float32 constants exactly as the reference builds them:
    const float PI_F     = 3.14159274101257324f;   // np.float32(np.pi)
    const float TWOPI    = 6.28318548202514648f;   // 2*pi_f
    const float FOUR_PI2 = (4.0f * PI_F) * PI_F;   // np.float32(4)*pi*pi

    float accR = 0.0f, accI = 0.0f;

    // Fixed trip count + branchless body: the unrolled iterations are fully
    // independent instruction streams the scheduler can pipeline.
#pragma unroll 4
    for (int n = 0; n < TRI_CHUNK; ++n) {
        eval_tri(U, V, sA[n], sB[n], accR, accI, TWOPI, FOUR_PI2);
    }

    ws[((size_t)q * BB + b) * NFREQ + p] = make_float2(accR, accI);
}

__global__ __launch_bounds__(BLK) void poly_cft_finalize(
    const float2* __restrict__ ws,   // [QQ][BB][NFREQ]
    const int*    __restrict__ lengths,
    float*        __restrict__ out)  // [2*64*2048]
{
    const int idx = blockIdx.x * BLK + threadIdx.x;  // 0..131071
    const int b = idx >> 11;
    const int p = idx & (NFREQ - 1);
    const int h = p >> 5;

    // Only chunks with work were written; loop bound is block-uniform
    // (b is constant within a 256-thread block).
    const int QN = (lengths[b] + TRI_CHUNK - 1) / TRI_CHUNK;

    float accR = 0.0f, accI = 0.0f;
    for (int q = 0; q < QN; ++q) {
        float2 v = ws[((size_t)q * BB + b) * NFREQ + p];
        accR += v.x;
        accI += v.y;
    }
    // numpy's masked segment-sum adds exact +0.0 for every invalid slot,
    // which flips -0.0 -> +0.0; reproduce that (affects only zero signs).
    accR += 0.0f;
    accI += 0.0f;

    if (h == 63) { accR = 0.0f; accI = 0.0f; }   // pad row

    const float m2 = __fadd_rn(__fmul_rn(accR, accR), __fmul_rn(accI, accI));
    float mag, ph;
    if (m2 == 0.0f) {
        mag = 0.0f;
        ph  = atan2f(accI, 1.0f);   // angle(0) = 0 semantics
    } else {
        mag = log1pf(sqrtf(m2));
        ph  = atan2f(accI, accR);
    }

    out[idx]              = mag;   // mag block [64,1,64,32]
    out[BB * NFREQ + idx] = ph;    // phase block follows
}

extern "C" void kernel_launch(void* const* d_in, const int* in_sizes, int n_in,
                              void* d_out, int out_size, void* d_ws, size_t ws_size,
                              hipStream_t stream) {
    const float* tris    = (const float*)d_in[0]; // [64,128,3,2] f32
    const int*   lengths = (const int*)d_in[1];   // [64] i32
    float*       out     = (float*)d_out;         // [2*64*2048] f32

    float2* partial = (float2*)d_ws;                        // 8 MB
    float4* triA    = (float4*)(partial + PARTIAL_F2);      // 128 KB
    float4* triB    = triA + NTRI;                          // 128 KB
    float*  Wtab    = (float*)(triB + NTRI);                // 96 floats

    poly_cft_setup<<<dim3(1), dim3(BLK), 0, stream>>>(tris, triA, triB, Wtab);
    poly_cft_partial<<<dim3(PCHUNKS, QQ, BB), dim3(BLK), 0, stream>>>(lengths, triA, triB, Wtab, partial);
    poly_cft_finalize<<<dim3(BB * NFREQ / BLK), dim3(BLK), 0, stream>>>(partial, lengths, out);
}

// Round 9
// 79.748 us; speedup vs baseline: 1.1061x; 1.1061x over previous
//
#include <hip/hip_runtime.h>
#include <cmath>

// Problem constants (fixed by the reference's init kwargs):
//   POS_FREQS=31, W_MIN=0.1, W_MAX=1.0, PATCH=16 -> grid H=64 (row 63 padded), W=32
//   batch_triangles: [64,128,3,2] f32, lengths: [64] i32
//   outputs: mag [64,1,64,32] f32 then phase [64,1,64,32] f32, concatenated flat.
#define BB     64
#define MAXN   128
#define HH     64
#define WW     32
#define NFREQ  (HH*WW)      // 2048
#define BLK    256
#define PCHUNKS (NFREQ/BLK) // 8 point-chunks per batch elem (1 point/thread)
#define TRI_CHUNK 16
#define QQ     (MAXN/TRI_CHUNK) // 8 triangle chunks
// workspace: float2 partial[QQ][BB][NFREQ] = 8*64*2048*8 B = 8 MB

// sin(2*pi*x), cos(2*pi*x) via hardware v_sin_f32/v_cos_f32 (input in
// REVOLUTIONS, reduced to [0,1) with v_fract_f32 first).
__device__ __forceinline__ void sincos_2pi(float x, float* s, float* c) {
    float r = __builtin_amdgcn_fractf(x);
    *s = __builtin_amdgcn_sinf(r);
    *c = __builtin_amdgcn_cosf(r);
}

// Fully BRANCHLESS (point, triangle) evaluation — IDENTICAL text to the
// round-5 passing kernel (absmax 0.015625). Do not perturb.
// Rotated frame: E_x = exp(-2*pi*i*t_x), t_q = U*xq+V*yq, t_r = t_q+U_,
// t_s = t_r+V_.  All four reference cases share:
//   re =  A*c_s + B*c_r + C*c_q + D*s_r + E*s_q
//   im = -A*s_s - B*s_r - C*s_q + D*c_r + E*c_q
// with k = sgn*area/(4pi^2*den):
//   normal: A=-U_, B=S,  C=-V_, D=0,     E=0;     den=U_*V_*S, sgn=+2
//   diag  : A=0,   B=1,  C=-1,  D=0,     E=2piU_; den=U_^2,    sgn=-2
//   u_mask: A=1,   B=0,  C=-1,  D=0,     E=2piV_; den=V_^2,    sgn=-2
//   v_mask: A=0,   B=1,  C=-1,  D=2piU_, E=0;     den=U_^2,    sgn=+2
//   zero  : k=0, add area directly.
__device__ __forceinline__ void eval_tri(
    float U, float V, float4 A4, float4 B4, float& accR, float& accI,
    float TWOPI, float FOUR_PI2)
{
    const float xq = A4.x,  yq = A4.y,  e1x = A4.z, e1y = A4.w;
    const float e2x = B4.x, e2y = B4.y, area = B4.z;

    // Mask-determining quantities: plain mul/mul/add (no FMA contraction)
    // to reproduce the reference's exact-zero pattern.
    const float U_ = __fadd_rn(__fmul_rn(U, e1x), __fmul_rn(V, e1y));
    const float V_ = __fadd_rn(__fmul_rn(U, e2x), __fmul_rn(V, e2y));
    const float S  = __fadd_rn(U_, V_);

    const bool uz   = (U_ == 0.0f);
    const bool vz   = (V_ == 0.0f);
    const bool sz   = (S  == 0.0f);
    const bool zero = uz && vz;
    const bool diag = sz && !zero;      // uz -> (sz<->vz), so cases exclusive
    const bool u_m  = uz && !zero;
    const bool v_m  = vz && !zero;
    const bool nrm  = !(uz || vz || sz);

    // Exponential args (not mask-relevant; FMA fine). t_r/t_s exact when
    // U_/V_ are exactly 0 (adding exact zero), which the special cases need.
    const float t_q = U * xq + V * yq;
    const float t_r = t_q + U_;
    const float t_s = t_r + V_;

    float s_q, c_q, s_r, c_r, s_s, c_s;
    sincos_2pi(t_q, &s_q, &c_q);
    sincos_2pi(t_r, &s_r, &c_r);
    sincos_2pi(t_s, &s_s, &c_s);

    const float twU = TWOPI * U_;
    const float twV = TWOPI * V_;

    const float Ac = nrm ? -U_ : (u_m ? 1.0f : 0.0f);
    const float Bc = nrm ?  S  : ((diag || v_m) ? 1.0f : 0.0f);
    const float Cc = nrm ? -V_ : -1.0f;
    const float Dc = v_m  ? twU : 0.0f;
    const float Ec = diag ? twU : (u_m ? twV : 0.0f);

    const float d1  = u_m ? V_ : U_;
    const float den = nrm ? (U_ * V_) * S : d1 * d1;
    const float p1  = __builtin_amdgcn_rcpf(FOUR_PI2 * den);
    const float sgn = (diag || u_m) ? -2.0f : 2.0f;
    const float k   = zero ? 0.0f : sgn * area * p1;   // cndmask kills inf path

    const float re =  Ac * c_s + Bc * c_r + Cc * c_q + Dc * s_r + Ec * s_q;
    const float im = -(Ac * s_s + Bc * s_r + Cc * s_q) + Dc * c_r + Ec * c_q;

    accR = fmaf(k, re, accR) + (zero ? area : 0.0f);
    accI = fmaf(k, im, accI);
}

// R5 structure exactly; ONLY experimental variable vs R5: __launch_bounds__
// second arg = 4 waves/EU (16 waves/CU) -> VGPR budget ~128 so the compiler
// can keep the 4 unrolled eval chains in flight instead of serializing them
// into 24 VGPRs.
__global__ __launch_bounds__(BLK, 4) void poly_cft_partial(
    const float* __restrict__ tris,    // [64,128,3,2]
    const int*   __restrict__ lengths, // [64]
    float2*      __restrict__ ws)      // [QQ][BB][NFREQ] partial sums
{
    __shared__ float4 sA[TRI_CHUNK];  // xq, yq, e1x=xr-xq, e1y=yr-yq
    __shared__ float4 sB[TRI_CHUNK];  // e2x=xs-xr, e2y=ys-yr, area, unused
    __shared__ float  s_posw[31];

    const int pc = blockIdx.x;                 // 0..7 point chunk
    const int q  = blockIdx.y;                 // 0..7 triangle chunk
    const int b  = blockIdx.z;                 // 0..63 batch elem
    const int p  = (pc << 8) | threadIdx.x;    // 0..2047 freq point
    const int h  = p >> 5;
    const int w  = p & 31;

    const int N   = lengths[b];
    const int n0  = q * TRI_CHUNK;
    const int cnt = min(n0 + TRI_CHUNK, N) - n0;   // may be <= 0

    // Entire chunk out of range: nothing to do — finalize only reads chunks
    // q < ceil(N/TRI_CHUNK), so no zero-write is needed.
    if (cnt <= 0) return;

    // Frequency grid values, matching numpy exactly:
    //   g = (1.0/0.1)**(1/30) in double; pos_w[k] = float32(0.1 * g**k)
    // (per-block cost is fully overlapped at 16 blocks/CU — measured R7:
    // hoisting this to a serial setup kernel was a net loss)
    if (threadIdx.x < 31) {
        double g = pow(10.0, 1.0 / 30.0);
        s_posw[threadIdx.x] = (float)(0.1 * pow(g, (double)threadIdx.x));
    }

    // Stage TRI_CHUNK triangles; pad invalid slots with degenerate zeros
    // (U_=V_=0 -> zero case -> contributes exactly area=0).
    if (threadIdx.x < TRI_CHUNK) {
        if ((int)threadIdx.x < cnt) {
            const float* t = tris + ((size_t)b * MAXN + n0 + threadIdx.x) * 6;
            float xq = t[0], yq = t[1];
            float xr = t[2], yr = t[3];
            float xs = t[4], ys = t[5];
            float det  = xq * (yr - ys) + xr * (ys - yq) + xs * (yq - yr);
            float area = fabsf(0.5f * det);
            sA[threadIdx.x] = make_float4(xq, yq, xr - xq, yr - yq);
            sB[threadIdx.x] = make_float4(xs - xr, ys - yr, area, 0.0f);
        } else {
            sA[threadIdx.x] = make_float4(0.0f, 0.0f, 0.0f, 0.0f);
            sB[threadIdx.x] = make_float4(0.0f, 0.0f, 0.0f, 0.0f);
        }
    }
    __syncthreads();

    // U = Wx[h], V = Wy[w]
    float U;
    if (h < 31)       U = -s_posw[30 - h];
    else if (h == 31) U = 0.0f;
    else if (h < 63)  U = s_posw[h - 32];
    else              U = 0.0f;   // padded row (masked in finalize)
    const float V = (w == 0) ? 0.0f : s_posw[w - 1];

    // float32 constants exactly as the reference builds them:
    const float PI_F     = 3.14159274101257324f;   // np.float32(np.pi)
    const float TWOPI    = 6.28318548202514648f;   // 2*pi_f
    const float FOUR_PI2 = (4.0f * PI_F) * PI_F;   // np.float32(4)*pi*pi

    float accR = 0.0f, accI = 0.0f;

    // Fixed trip count + branchless body: with the raised VGPR budget the
    // unrolled iterations can genuinely pipeline.
#pragma unroll 4
    for (int n = 0; n < TRI_CHUNK; ++n) {
        eval_tri(U, V, sA[n], sB[n], accR, accI, TWOPI, FOUR_PI2);
    }

    ws[((size_t)q * BB + b) * NFREQ + p] = make_float2(accR, accI);
}

__global__ __launch_bounds__(BLK) void poly_cft_finalize(
    const float2* __restrict__ ws,   // [QQ][BB][NFREQ]
    const int*    __restrict__ lengths,
    float*        __restrict__ out)  // [2*64*2048]
{
    const int idx = blockIdx.x * BLK + threadIdx.x;  // 0..131071
    const int b = idx >> 11;
    const int p = idx & (NFREQ - 1);
    const int h = p >> 5;

    // Only chunks with work were written; loop bound is block-uniform
    // (b is constant within a 256-thread block).
    const int QN = (lengths[b] + TRI_CHUNK - 1) / TRI_CHUNK;

    float accR = 0.0f, accI = 0.0f;
    for (int q = 0; q < QN; ++q) {
        float2 v = ws[((size_t)q * BB + b) * NFREQ + p];
        accR += v.x;
        accI += v.y;
    }
    // numpy's masked segment-sum adds exact +0.0 for every invalid slot,
    // which flips -0.0 -> +0.0; reproduce that (affects only zero signs).
    accR += 0.0f;
    accI += 0.0f;

    if (h == 63) { accR = 0.0f; accI = 0.0f; }   // pad row

    const float m2 = __fadd_rn(__fmul_rn(accR, accR), __fmul_rn(accI, accI));
    float mag, ph;
    if (m2 == 0.0f) {
        mag = 0.0f;
        ph  = atan2f(accI, 1.0f);   // angle(0) = 0 semantics
    } else {
        mag = log1pf(sqrtf(m2));
        ph  = atan2f(accI, accR);
    }

    out[idx]              = mag;   // mag block [64,1,64,32]
    out[BB * NFREQ + idx] = ph;    // phase block follows
}

extern "C" void kernel_launch(void* const* d_in, const int* in_sizes, int n_in,
                              void* d_out, int out_size, void* d_ws, size_t ws_size,
                              hipStream_t stream) {
    const float* tris    = (const float*)d_in[0]; // [64,128,3,2] f32
    const int*   lengths = (const int*)d_in[1];   // [64] i32
    float*       out     = (float*)d_out;         // [2*64*2048] f32
    float2*      partial = (float2*)d_ws;         // 8 MB of scratch

    poly_cft_partial<<<dim3(PCHUNKS, QQ, BB), dim3(BLK), 0, stream>>>(tris, lengths, partial);
    poly_cft_finalize<<<dim3(BB * NFREQ / BLK), dim3(BLK), 0, stream>>>(partial, lengths, out);
}

// Round 10
// 76.951 us; speedup vs baseline: 1.1463x; 1.0363x over previous
//
#include <hip/hip_runtime.h>
#include <cmath>

// Problem constants (fixed by the reference's init kwargs):
//   POS_FREQS=31, W_MIN=0.1, W_MAX=1.0, PATCH=16 -> grid H=64 (row 63 padded), W=32
//   batch_triangles: [64,128,3,2] f32, lengths: [64] i32
//   outputs: mag [64,1,64,32] f32 then phase [64,1,64,32] f32, concatenated flat.
#define BB     64
#define MAXN   128
#define HH     64
#define WW     32
#define NFREQ  (HH*WW)      // 2048
#define BLK    256
#define NWAVE  4            // waves per block; each wave = 64 points' lanes
#define PGRPS  (NFREQ/64)   // 32 point-groups of 64 points per batch elem

// sin(2*pi*x), cos(2*pi*x) via hardware v_sin_f32/v_cos_f32 (input in
// REVOLUTIONS, reduced to [0,1) with v_fract_f32 first).
__device__ __forceinline__ void sincos_2pi(float x, float* s, float* c) {
    float r = __builtin_amdgcn_fractf(x);
    *s = __builtin_amdgcn_sinf(r);
    *c = __builtin_amdgcn_cosf(r);
}

// Fully BRANCHLESS (point, triangle) evaluation — IDENTICAL text to the
// round-5/8 passing kernels (absmax 0.015625). Do not perturb.
// Rotated frame: E_x = exp(-2*pi*i*t_x), t_q = U*xq+V*yq, t_r = t_q+U_,
// t_s = t_r+V_.  All four reference cases share:
//   re =  A*c_s + B*c_r + C*c_q + D*s_r + E*s_q
//   im = -A*s_s - B*s_r - C*s_q + D*c_r + E*c_q
// with k = sgn*area/(4pi^2*den):
//   normal: A=-U_, B=S,  C=-V_, D=0,     E=0;     den=U_*V_*S, sgn=+2
//   diag  : A=0,   B=1,  C=-1,  D=0,     E=2piU_; den=U_^2,    sgn=-2
//   u_mask: A=1,   B=0,  C=-1,  D=0,     E=2piV_; den=V_^2,    sgn=-2
//   v_mask: A=0,   B=1,  C=-1,  D=2piU_, E=0;     den=U_^2,    sgn=+2
//   zero  : k=0, add area directly.
__device__ __forceinline__ void eval_tri(
    float U, float V, float4 A4, float4 B4, float& accR, float& accI,
    float TWOPI, float FOUR_PI2)
{
    const float xq = A4.x,  yq = A4.y,  e1x = A4.z, e1y = A4.w;
    const float e2x = B4.x, e2y = B4.y, area = B4.z;

    // Mask-determining quantities: plain mul/mul/add (no FMA contraction)
    // to reproduce the reference's exact-zero pattern.
    const float U_ = __fadd_rn(__fmul_rn(U, e1x), __fmul_rn(V, e1y));
    const float V_ = __fadd_rn(__fmul_rn(U, e2x), __fmul_rn(V, e2y));
    const float S  = __fadd_rn(U_, V_);

    const bool uz   = (U_ == 0.0f);
    const bool vz   = (V_ == 0.0f);
    const bool sz   = (S  == 0.0f);
    const bool zero = uz && vz;
    const bool diag = sz && !zero;      // uz -> (sz<->vz), so cases exclusive
    const bool u_m  = uz && !zero;
    const bool v_m  = vz && !zero;
    const bool nrm  = !(uz || vz || sz);

    // Exponential args (not mask-relevant; FMA fine). t_r/t_s exact when
    // U_/V_ are exactly 0 (adding exact zero), which the special cases need.
    const float t_q = U * xq + V * yq;
    const float t_r = t_q + U_;
    const float t_s = t_r + V_;

    float s_q, c_q, s_r, c_r, s_s, c_s;
    sincos_2pi(t_q, &s_q, &c_q);
    sincos_2pi(t_r, &s_r, &c_r);
    sincos_2pi(t_s, &s_s, &c_s);

    const float twU = TWOPI * U_;
    const float twV = TWOPI * V_;

    const float Ac = nrm ? -U_ : (u_m ? 1.0f : 0.0f);
    const float Bc = nrm ?  S  : ((diag || v_m) ? 1.0f : 0.0f);
    const float Cc = nrm ? -V_ : -1.0f;
    const float Dc = v_m  ? twU : 0.0f;
    const float Ec = diag ? twU : (u_m ? twV : 0.0f);

    const float d1  = u_m ? V_ : U_;
    const float den = nrm ? (U_ * V_) * S : d1 * d1;
    const float p1  = __builtin_amdgcn_rcpf(FOUR_PI2 * den);
    const float sgn = (diag || u_m) ? -2.0f : 2.0f;
    const float k   = zero ? 0.0f : sgn * area * p1;   // cndmask kills inf path

    const float re =  Ac * c_s + Bc * c_r + Cc * c_q + Dc * s_r + Ec * s_q;
    const float im = -(Ac * s_s + Bc * s_r + Cc * s_q) + Dc * c_r + Ec * c_q;

    accR = fmaf(k, re, accR) + (zero ? area : 0.0f);
    accI = fmaf(k, im, accI);
}

// ONE fused kernel:
//   block = 256 thr = 4 waves; the 4 waves share 64 points (lane -> point)
//   and split the triangle list stride-4 (wave-uniform index -> scalar
//   loads, no LDS staging, no barriers in the loop). 2 KB LDS reduction
//   4 waves -> 1, then mag/phase written directly. No workspace, one launch.
__global__ __launch_bounds__(BLK) void poly_cft_fused(
    const float* __restrict__ tris,    // [64,128,3,2]
    const int*   __restrict__ lengths, // [64]
    float*       __restrict__ out)     // [2*64*2048]
{
    __shared__ float  s_posw[31];
    __shared__ float2 s_red[NWAVE][64];   // 2 KB; float2 stride -> 2-way (free)

    const int pg   = blockIdx.x;           // 0..31 point group
    const int b    = blockIdx.y;           // 0..63 batch elem
    const int lane = threadIdx.x & 63;
    const int wv   = threadIdx.x >> 6;     // 0..3 wave id
    const int p    = (pg << 6) | lane;     // 0..2047 freq point
    const int h    = p >> 5;
    const int w    = p & 31;

    // Frequency grid values, matching numpy exactly:
    //   g = (1.0/0.1)**(1/30) in double; pos_w[k] = float32(0.1 * g**k)
    // (per-block cost ~overlapped at 8 blocks/CU — hoisting measured a loss, R7)
    if (threadIdx.x < 31) {
        double g = pow(10.0, 1.0 / 30.0);
        s_posw[threadIdx.x] = (float)(0.1 * pow(g, (double)threadIdx.x));
    }
    __syncthreads();

    // U = Wx[h], V = Wy[w]
    float U;
    if (h < 31)       U = -s_posw[30 - h];
    else if (h == 31) U = 0.0f;
    else if (h < 63)  U = s_posw[h - 32];
    else              U = 0.0f;   // padded row (masked before output)
    const float V = (w == 0) ? 0.0f : s_posw[w - 1];

    // float32 constants exactly as the reference builds them:
    const float PI_F     = 3.14159274101257324f;   // np.float32(np.pi)
    const float TWOPI    = 6.28318548202514648f;   // 2*pi_f
    const float FOUR_PI2 = (4.0f * PI_F) * PI_F;   // np.float32(4)*pi*pi

    const int N = lengths[b];
    const float* __restrict__ tb = tris + (size_t)b * MAXN * 6;

    float accR = 0.0f, accI = 0.0f;

    // Wave wv handles triangles n = wv, wv+4, wv+8, ... (wave-uniform index;
    // readfirstlane forces the scalar-load path: s_load from L2-resident tris).
#pragma unroll 2
    for (int n = wv; n < N; n += NWAVE) {
        const int nn = __builtin_amdgcn_readfirstlane(n);
        const float* t = tb + nn * 6;
        const float xq = t[0], yq = t[1];
        const float xr = t[2], yr = t[3];
        const float xs = t[4], ys = t[5];
        const float det  = xq * (yr - ys) + xr * (ys - yq) + xs * (yq - yr);
        const float area = fabsf(0.5f * det);
        const float4 A4 = make_float4(xq, yq, xr - xq, yr - yq);
        const float4 B4 = make_float4(xs - xr, ys - yr, area, 0.0f);
        eval_tri(U, V, A4, B4, accR, accI, TWOPI, FOUR_PI2);
    }

    s_red[wv][lane] = make_float2(accR, accI);
    __syncthreads();

    if (wv == 0) {
        float R = 0.0f, I = 0.0f;
#pragma unroll
        for (int k = 0; k < NWAVE; ++k) {
            const float2 v = s_red[k][lane];
            R += v.x;
            I += v.y;
        }
        // numpy's masked segment-sum adds exact +0.0 for invalid slots,
        // flipping -0.0 -> +0.0; reproduce (affects only zero signs).
        R += 0.0f;
        I += 0.0f;

        if (h == 63) { R = 0.0f; I = 0.0f; }   // pad row

        const float m2 = __fadd_rn(__fmul_rn(R, R), __fmul_rn(I, I));
        float mag, ph;
        if (m2 == 0.0f) {
            mag = 0.0f;
            ph  = atan2f(I, 1.0f);   // angle(0) = 0 semantics
        } else {
            mag = log1pf(sqrtf(m2));
            ph  = atan2f(I, R);
        }

        const int o = b * NFREQ + p;
        out[o]              = mag;   // mag block [64,1,64,32]
        out[BB * NFREQ + o] = ph;    // phase block follows
    }
}

extern "C" void kernel_launch(void* const* d_in, const int* in_sizes, int n_in,
                              void* d_out, int out_size, void* d_ws, size_t ws_size,
                              hipStream_t stream) {
    const float* tris    = (const float*)d_in[0]; // [64,128,3,2] f32
    const int*   lengths = (const int*)d_in[1];   // [64] i32
    float*       out     = (float*)d_out;         // [2*64*2048] f32

    poly_cft_fused<<<dim3(PGRPS, BB), dim3(BLK), 0, stream>>>(tris, lengths, out);
}